// Round 1
// baseline (4457.158 us; speedup 1.0000x reference)
//
#include <hip/hip_runtime.h>
#include <math.h>

#define T_LEN   1024
#define S_SEAS  168
#define H_SZ    128
#define G_SZ    512   // 4*H
#define WIN_SZ  168
#define OUT_SZ  24
#define N_WIN   833
#define BB      8
#define NBLK    ((N_WIN + BB - 1) / BB)

__device__ __forceinline__ float sigmoidf_(float v) {
    return 1.0f / (1.0f + expf(-v));
}

// ---------------------------------------------------------------------------
// Phase A: Holt-Winters ES scan (inherently sequential, 1024 steps).
// Writes levels[0:1024] and ws[0:1024] exactly per reference semantics:
//   ws[t] = w_init[t] (t<168); ws[168] = w_init[0]; ws[t] = nw_{t-168} (t>168)
// ---------------------------------------------------------------------------
__global__ void es_scan_kernel(const float* __restrict__ x,
                               const float* __restrict__ lvl_raw,
                               const float* __restrict__ seas_raw,
                               const float* __restrict__ seas_params,
                               float* __restrict__ levels,
                               float* __restrict__ wsv) {
    __shared__ float buf[S_SEAS];
    const int t = threadIdx.x;
    for (int i = t; i < S_SEAS; i += blockDim.x) {
        const float w = expf(seas_params[i]);
        buf[i] = w;
        wsv[i] = w;
    }
    __syncthreads();
    if (t == 0) {
        const float a = 1.0f / (1.0f + expf(-lvl_raw[0]));
        const float g = 1.0f / (1.0f + expf(-seas_raw[0]));
        float level = x[0] / buf[0];
        levels[0] = level;
        wsv[S_SEAS] = buf[0];   // ws_full[168] = w_init[0]
        for (int i = 1; i < T_LEN; ++i) {
            const int j = i % S_SEAS;
            const float w  = buf[j];
            const float xi = x[i];
            const float nl = (a * xi) / w + (1.0f - a) * level;
            const float nw = (g * xi) / nl + (1.0f - g) * w;
            buf[j] = nw;
            levels[i] = nl;
            if (i + S_SEAS < T_LEN) wsv[i + S_SEAS] = nw;
            level = nl;
        }
    }
}

// ---------------------------------------------------------------------------
// Phase B: deseasonalized log inputs (time-major sq_inT [168][833]) + labels
// (directly into d_out) + level_var_loss scalar.
// ---------------------------------------------------------------------------
__global__ __launch_bounds__(256) void window_kernel(
    const float* __restrict__ x,
    const float* __restrict__ levels,
    const float* __restrict__ wsv,
    const float* __restrict__ noise_in,
    const float* __restrict__ noise_lab,
    float* __restrict__ sqT,
    float* __restrict__ outbuf) {
    const int p = blockIdx.x;   // 0..167: window pos; 168..191: label pos
    for (int nn = threadIdx.x; nn < N_WIN; nn += 256) {
        const float lev = levels[nn + WIN_SZ];
        if (p < WIN_SZ) {
            const int tt = nn + p;
            sqT[p * N_WIN + nn] =
                logf(x[tt] / (lev * wsv[tt])) + noise_in[nn * WIN_SZ + p];
        } else {
            const int o = p - WIN_SZ;
            const int tt = nn + WIN_SZ + o;
            outbuf[N_WIN * OUT_SZ + nn * OUT_SZ + o] =
                logf(x[tt] / (lev * wsv[tt])) + noise_lab[nn * OUT_SZ + o];
        }
    }
    if (blockIdx.x == 0 && threadIdx.x == 0)
        outbuf[2 * N_WIN * OUT_SZ] = 0.0f;   // level_var_loss
}

// ---------------------------------------------------------------------------
// Weight prep: pack Wh0/Wx1/Wh1 [512][128] -> [k/4][j][4] so LSTM thread j
// loads 4 consecutive k-weights as one coalesced dwordx4. Also tanh_W^T.
// ---------------------------------------------------------------------------
__global__ void prep_weights(const float* __restrict__ Wh0,
                             const float* __restrict__ Wx1,
                             const float* __restrict__ Wh1,
                             const float* __restrict__ tanhW,
                             float* __restrict__ Wh0p,
                             float* __restrict__ Wx1p,
                             float* __restrict__ Wh1p,
                             float* __restrict__ tanhWT) {
    const int idx = blockIdx.x * 256 + threadIdx.x;
    if (idx < G_SZ * H_SZ) {
        const int j = idx >> 7, k = idx & (H_SZ - 1);
        const int o = (k >> 2) * (G_SZ * 4) + j * 4 + (k & 3);
        Wh0p[o] = Wh0[idx];
        Wx1p[o] = Wx1[idx];
        Wh1p[o] = Wh1[idx];
    }
    if (idx < H_SZ * H_SZ) {
        const int m = idx >> 7, k = idx & (H_SZ - 1);
        tanhWT[k * H_SZ + m] = tanhW[idx];
    }
}

// ---------------------------------------------------------------------------
// Phase C: fused 2-layer LSTM. Each block owns BB=8 windows for all 168
// steps; h/c state in LDS; thread j computes gate column j for all 8 windows.
// ---------------------------------------------------------------------------
__global__ __launch_bounds__(512) void lstm_kernel(
    const float* __restrict__ sqT,
    const float* __restrict__ Wx0,
    const float* __restrict__ b0v,
    const float* __restrict__ Wh0p,
    const float* __restrict__ Wx1p,
    const float* __restrict__ Wh1p,
    const float* __restrict__ b1v,
    float* __restrict__ hfin) {
    __shared__ alignas(16) float h0s[BB][H_SZ];
    __shared__ alignas(16) float c0s[BB][H_SZ];
    __shared__ alignas(16) float h1s[BB][H_SZ];
    __shared__ alignas(16) float c1s[BB][H_SZ];
    __shared__ alignas(16) float gbuf[BB][G_SZ];
    __shared__ float xts[BB];

    const int tid = threadIdx.x;     // = gate column j
    const int base = blockIdx.x * BB;

    for (int i = tid; i < BB * H_SZ; i += 512) {
        (&h0s[0][0])[i] = 0.0f;
        (&c0s[0][0])[i] = 0.0f;
        (&h1s[0][0])[i] = 0.0f;
        (&c1s[0][0])[i] = 0.0f;
    }
    const float wx0 = Wx0[tid];
    const float bb0 = b0v[tid];
    const float bb1 = b1v[tid];
    __syncthreads();

    for (int t = 0; t < WIN_SZ; ++t) {
        if (tid < BB) {
            const int nn = base + tid;
            xts[tid] = (nn < N_WIN) ? sqT[t * N_WIN + nn] : 0.0f;
        }
        __syncthreads();

        // -------- layer 0 gates: gbuf[b][j] = b0[j] + Wx0[j]*x_t[b] + h0.Wh0^T
        float acc[BB];
#pragma unroll
        for (int b = 0; b < BB; ++b) acc[b] = bb0 + wx0 * xts[b];
        for (int k4 = 0; k4 < H_SZ; k4 += 4) {
            const float4 w = *(const float4*)(Wh0p + (k4 >> 2) * (G_SZ * 4) + tid * 4);
#pragma unroll
            for (int b = 0; b < BB; ++b) {
                const float4 h = *(const float4*)(&h0s[b][k4]);
                acc[b] += h.x * w.x + h.y * w.y + h.z * w.z + h.w * w.w;
            }
        }
#pragma unroll
        for (int b = 0; b < BB; ++b) gbuf[b][tid] = acc[b];
        __syncthreads();

        // -------- layer 0 cell/hidden update (gate order i,f,g,o)
#pragma unroll
        for (int u = 0; u < (BB * H_SZ) / 512; ++u) {
            const int idx = u * 512 + tid;
            const int b = idx >> 7, n = idx & (H_SZ - 1);
            const float ig = sigmoidf_(gbuf[b][n]);
            const float fg = sigmoidf_(gbuf[b][n + 128]);
            const float gg = tanhf(gbuf[b][n + 256]);
            const float og = sigmoidf_(gbuf[b][n + 384]);
            const float c = fg * c0s[b][n] + ig * gg;
            c0s[b][n] = c;
            h0s[b][n] = og * tanhf(c);
        }
        __syncthreads();

        // -------- layer 1 gates: x_t = h0 (new), recurrent = h1 (old)
#pragma unroll
        for (int b = 0; b < BB; ++b) acc[b] = bb1;
        for (int k4 = 0; k4 < H_SZ; k4 += 4) {
            const float4 wa = *(const float4*)(Wx1p + (k4 >> 2) * (G_SZ * 4) + tid * 4);
            const float4 wb = *(const float4*)(Wh1p + (k4 >> 2) * (G_SZ * 4) + tid * 4);
#pragma unroll
            for (int b = 0; b < BB; ++b) {
                const float4 ha = *(const float4*)(&h0s[b][k4]);
                const float4 hb = *(const float4*)(&h1s[b][k4]);
                acc[b] += ha.x * wa.x + ha.y * wa.y + ha.z * wa.z + ha.w * wa.w;
                acc[b] += hb.x * wb.x + hb.y * wb.y + hb.z * wb.z + hb.w * wb.w;
            }
        }
#pragma unroll
        for (int b = 0; b < BB; ++b) gbuf[b][tid] = acc[b];
        __syncthreads();

        // -------- layer 1 update
#pragma unroll
        for (int u = 0; u < (BB * H_SZ) / 512; ++u) {
            const int idx = u * 512 + tid;
            const int b = idx >> 7, n = idx & (H_SZ - 1);
            const float ig = sigmoidf_(gbuf[b][n]);
            const float fg = sigmoidf_(gbuf[b][n + 128]);
            const float gg = tanhf(gbuf[b][n + 256]);
            const float og = sigmoidf_(gbuf[b][n + 384]);
            const float c = fg * c1s[b][n] + ig * gg;
            c1s[b][n] = c;
            h1s[b][n] = og * tanhf(c);
        }
        __syncthreads();
    }

    // write final layer-1 hidden
    for (int i = tid; i < BB * H_SZ; i += 512) {
        const int b = i >> 7, k = i & (H_SZ - 1);
        const int nn = base + b;
        if (nn < N_WIN) hfin[nn * H_SZ + k] = h1s[b][k];
    }
}

// ---------------------------------------------------------------------------
// Phase D: head — feat = tanh(h @ tanh_W^T + tanh_b); out = feat @ lin_W^T + lin_b
// ---------------------------------------------------------------------------
__global__ __launch_bounds__(128) void head_kernel(
    const float* __restrict__ hfin,
    const float* __restrict__ tanhWT,
    const float* __restrict__ tanhB,
    const float* __restrict__ linW,
    const float* __restrict__ linB,
    float* __restrict__ out) {
    __shared__ float hl[H_SZ];
    __shared__ float fl[H_SZ];
    const int nn = blockIdx.x;
    const int m = threadIdx.x;
    hl[m] = hfin[nn * H_SZ + m];
    __syncthreads();
    float acc = tanhB[m];
    for (int k = 0; k < H_SZ; ++k) acc += hl[k] * tanhWT[k * H_SZ + m];
    fl[m] = tanhf(acc);
    __syncthreads();
    if (m < OUT_SZ) {
        float a = linB[m];
        for (int k = 0; k < H_SZ; ++k) a += fl[k] * linW[m * H_SZ + k];
        out[nn * OUT_SZ + m] = a;
    }
}

// ---------------------------------------------------------------------------
extern "C" void kernel_launch(void* const* d_in, const int* in_sizes, int n_in,
                              void* d_out, int out_size, void* d_ws, size_t ws_size,
                              hipStream_t stream) {
    const float* x           = (const float*)d_in[0];
    const float* lvl_raw     = (const float*)d_in[1];
    const float* seas_raw    = (const float*)d_in[2];
    const float* seas_params = (const float*)d_in[3];
    const float* noise_in    = (const float*)d_in[4];
    const float* noise_lab   = (const float*)d_in[5];
    const float* Wx0         = (const float*)d_in[6];
    const float* Wh0         = (const float*)d_in[7];
    const float* b0v         = (const float*)d_in[8];
    const float* Wx1         = (const float*)d_in[9];
    const float* Wh1         = (const float*)d_in[10];
    const float* b1v         = (const float*)d_in[11];
    const float* tanhW       = (const float*)d_in[12];
    const float* tanhB       = (const float*)d_in[13];
    const float* linW        = (const float*)d_in[14];
    const float* linB        = (const float*)d_in[15];
    float* out = (float*)d_out;

    // workspace layout (floats)
    float* wsf    = (float*)d_ws;
    float* levels = wsf;                                   // 1024
    float* wsv    = levels + T_LEN;                        // 1024
    float* sqT    = wsv + T_LEN;                           // 168*833
    float* hfin   = sqT + WIN_SZ * N_WIN;                  // 833*128
    float* Wh0p   = hfin + N_WIN * H_SZ;                   // 512*128
    float* Wx1p   = Wh0p + G_SZ * H_SZ;                    // 512*128
    float* Wh1p   = Wx1p + G_SZ * H_SZ;                    // 512*128
    float* tanhWT = Wh1p + G_SZ * H_SZ;                    // 128*128

    hipLaunchKernelGGL(es_scan_kernel, dim3(1), dim3(256), 0, stream,
                       x, lvl_raw, seas_raw, seas_params, levels, wsv);
    hipLaunchKernelGGL(prep_weights, dim3(256), dim3(256), 0, stream,
                       Wh0, Wx1, Wh1, tanhW, Wh0p, Wx1p, Wh1p, tanhWT);
    hipLaunchKernelGGL(window_kernel, dim3(WIN_SZ + OUT_SZ), dim3(256), 0, stream,
                       x, levels, wsv, noise_in, noise_lab, sqT, out);
    hipLaunchKernelGGL(lstm_kernel, dim3(NBLK), dim3(512), 0, stream,
                       sqT, Wx0, b0v, Wh0p, Wx1p, Wh1p, b1v, hfin);
    hipLaunchKernelGGL(head_kernel, dim3(N_WIN), dim3(128), 0, stream,
                       hfin, tanhWT, tanhB, linW, linB, out);
}

// Round 2
// 859.836 us; speedup vs baseline: 5.1837x; 5.1837x over previous
//
#include <hip/hip_runtime.h>
#include <math.h>

#define T_LEN   1024
#define S_SEAS  168
#define H_SZ    128
#define G_SZ    512   // 4*H
#define WIN_SZ  168
#define OUT_SZ  24
#define N_WIN   833
#define BB      16
#define NBLK    ((N_WIN + BB - 1) / BB)   // 53

typedef __attribute__((ext_vector_type(8))) __bf16 bf16x8;
typedef __attribute__((ext_vector_type(4))) float  f32x4;

__device__ __forceinline__ float fsig(float x) {
    return __fdividef(1.0f, 1.0f + __expf(-x));
}
__device__ __forceinline__ float ftanh(float x) {
    return 1.0f - __fdividef(2.0f, __expf(2.0f * x) + 1.0f);
}

// ---------------------------------------------------------------------------
// Phase A: Holt-Winters ES scan (inherently sequential, 1024 steps).
// ---------------------------------------------------------------------------
__global__ void es_scan_kernel(const float* __restrict__ x,
                               const float* __restrict__ lvl_raw,
                               const float* __restrict__ seas_raw,
                               const float* __restrict__ seas_params,
                               float* __restrict__ levels,
                               float* __restrict__ wsv) {
    __shared__ float buf[S_SEAS];
    const int t = threadIdx.x;
    for (int i = t; i < S_SEAS; i += blockDim.x) {
        const float w = expf(seas_params[i]);
        buf[i] = w;
        wsv[i] = w;
    }
    __syncthreads();
    if (t == 0) {
        const float a = 1.0f / (1.0f + expf(-lvl_raw[0]));
        const float g = 1.0f / (1.0f + expf(-seas_raw[0]));
        float level = x[0] / buf[0];
        levels[0] = level;
        wsv[S_SEAS] = buf[0];   // ws_full[168] = w_init[0]
        for (int i = 1; i < T_LEN; ++i) {
            const int j = i % S_SEAS;
            const float w  = buf[j];
            const float xi = x[i];
            const float nl = (a * xi) / w + (1.0f - a) * level;
            const float nw = (g * xi) / nl + (1.0f - g) * w;
            buf[j] = nw;
            levels[i] = nl;
            if (i + S_SEAS < T_LEN) wsv[i + S_SEAS] = nw;
            level = nl;
        }
    }
}

// ---------------------------------------------------------------------------
// Phase B: deseasonalized log inputs (time-major sq_inT [168][833]) + labels
// (directly into d_out) + level_var_loss scalar.
// ---------------------------------------------------------------------------
__global__ __launch_bounds__(256) void window_kernel(
    const float* __restrict__ x,
    const float* __restrict__ levels,
    const float* __restrict__ wsv,
    const float* __restrict__ noise_in,
    const float* __restrict__ noise_lab,
    float* __restrict__ sqT,
    float* __restrict__ outbuf) {
    const int p = blockIdx.x;   // 0..167: window pos; 168..191: label pos
    for (int nn = threadIdx.x; nn < N_WIN; nn += 256) {
        const float lev = levels[nn + WIN_SZ];
        if (p < WIN_SZ) {
            const int tt = nn + p;
            sqT[p * N_WIN + nn] =
                logf(x[tt] / (lev * wsv[tt])) + noise_in[nn * WIN_SZ + p];
        } else {
            const int o = p - WIN_SZ;
            const int tt = nn + WIN_SZ + o;
            outbuf[N_WIN * OUT_SZ + nn * OUT_SZ + o] =
                logf(x[tt] / (lev * wsv[tt])) + noise_lab[nn * OUT_SZ + o];
        }
    }
    if (blockIdx.x == 0 && threadIdx.x == 0)
        outbuf[2 * N_WIN * OUT_SZ] = 0.0f;   // level_var_loss
}

// ---------------------------------------------------------------------------
// Weight prep: pack Wh0 / [Wx1;Wh1] into per-lane bf16 MFMA B-fragments.
// B-frag for mfma_f32_16x16x32_bf16: lane l holds col n = (l&15), 8 contiguous
// k at (l>>4)*8 (m92/m97 ref-checked layout). Fragment f for wave w, gate-sub
// ns (i/f/g/o), K-tile kt lives at pw[f*64 + l] (16B per lane).
// Gate column for (w, ns, l): g = ns*128 + w*16 + (l&15).
// ---------------------------------------------------------------------------
__global__ __launch_bounds__(256) void prep_weights(
    const float* __restrict__ Wh0,
    const float* __restrict__ Wx1,
    const float* __restrict__ Wh1,
    const float* __restrict__ tanhW,
    uint4* __restrict__ pw0,
    uint4* __restrict__ pw1,
    float* __restrict__ tanhWT) {
    const int idx = blockIdx.x * 256 + threadIdx.x;
    auto bfr = [](float f) -> unsigned int {   // fp32 -> bf16 (RNE)
        union { float f; unsigned int u; } v; v.f = f;
        return ((v.u + 0x7FFFu + ((v.u >> 16) & 1u)) >> 16) & 0xFFFFu;
    };
    if (idx < 8192) {                       // pw0: Wh0, 128 frags (8w x 4ns x 4kt)
        const int l = idx & 63, f = idx >> 6;
        const int kt = f & 3, ns = (f >> 2) & 3, w = f >> 4;
        const int g = ns * 128 + w * 16 + (l & 15);
        const int kb = kt * 32 + (l >> 4) * 8;
        const float* s = Wh0 + g * H_SZ + kb;
        uint4 o;
        unsigned int* po = &o.x;
        for (int p = 0; p < 4; ++p) po[p] = bfr(s[2 * p]) | (bfr(s[2 * p + 1]) << 16);
        pw0[idx] = o;
    } else if (idx < 8192 + 16384) {        // pw1: [Wx1 (kt<4); Wh1 (kt>=4)], 256 frags
        const int j = idx - 8192;
        const int l = j & 63, f = j >> 6;
        const int kt = f & 7, ns = (f >> 3) & 3, w = f >> 5;
        const int g = ns * 128 + w * 16 + (l & 15);
        const float* srcm = (kt < 4) ? Wx1 : Wh1;
        const int kb = (kt & 3) * 32 + (l >> 4) * 8;
        const float* s = srcm + g * H_SZ + kb;
        uint4 o;
        unsigned int* po = &o.x;
        for (int p = 0; p < 4; ++p) po[p] = bfr(s[2 * p]) | (bfr(s[2 * p + 1]) << 16);
        pw1[j] = o;
    } else if (idx < 8192 + 16384 + 16384) {  // tanh_W transpose (fp32)
        const int j = idx - 8192 - 16384;
        const int m = j >> 7, k = j & 127;
        tanhWT[k * H_SZ + m] = tanhW[j];
    }
}

// ---------------------------------------------------------------------------
// Phase C: fused 2-layer MFMA LSTM.
// Block = 16 windows (M-tile), 8 waves; wave w owns hidden units [16w,16w+16).
// Weights live in VGPRs (loaded once); c-state lives in registers; h0/h1
// double-buffered bf16 in LDS (pitch 136 vs bank conflicts). 1 barrier/step.
// ---------------------------------------------------------------------------
__global__ __launch_bounds__(512, 2) void lstm_kernel(
    const float* __restrict__ sqT,
    const float* __restrict__ Wx0,
    const float* __restrict__ b0v,
    const float* __restrict__ b1v,
    const uint4* __restrict__ pw0,
    const uint4* __restrict__ pw1,
    float* __restrict__ hfin) {
    __shared__ __bf16 h0s[2][16][136];
    __shared__ __bf16 h1s[2][16][136];
    __shared__ float  xls[WIN_SZ][16];

    const int tid  = threadIdx.x;
    const int w    = tid >> 6;        // wave id: owns units [16w, 16w+16)
    const int lane = tid & 63;
    const int cc   = lane & 15;       // unit-within-wave / A-row (batch)
    const int kl   = lane >> 4;       // k-group; C rows = kl*4 + r (batch)
    const int base = blockIdx.x * BB;

    // stage x for all 168 steps: xls[t][m] = sqT[t][base+m]
    for (int i = tid; i < WIN_SZ * BB; i += 512) {
        const int t = i >> 4, m = i & 15;
        const int nn = base + m;
        xls[t][m] = (nn < N_WIN) ? sqT[t * N_WIN + nn] : 0.0f;
    }
    // zero initial hidden state (buffer 0 is read at t=0)
    for (int i = tid; i < 2 * 16 * 136; i += 512) {
        (&h0s[0][0][0])[i] = (__bf16)0.0f;
        (&h1s[0][0][0])[i] = (__bf16)0.0f;
    }

    // resident weights: wB0[ns][kt] (K=128), wB1[ns][kt] (K=256: Wx1 then Wh1)
    const bf16x8* p0 = (const bf16x8*)pw0;
    const bf16x8* p1 = (const bf16x8*)pw1;
    bf16x8 wB0[4][4];
    bf16x8 wB1[4][8];
#pragma unroll
    for (int ns = 0; ns < 4; ++ns)
#pragma unroll
        for (int kt = 0; kt < 4; ++kt)
            wB0[ns][kt] = p0[((w * 4 + ns) * 4 + kt) * 64 + lane];
#pragma unroll
    for (int ns = 0; ns < 4; ++ns)
#pragma unroll
        for (int kt = 0; kt < 8; ++kt)
            wB1[ns][kt] = p1[((w * 4 + ns) * 8 + kt) * 64 + lane];

    float b0r[4], wx0r[4], b1r[4];
#pragma unroll
    for (int ns = 0; ns < 4; ++ns) {
        const int g = ns * 128 + w * 16 + cc;
        b0r[ns]  = b0v[g];
        wx0r[ns] = Wx0[g];
        b1r[ns]  = b1v[g];
    }
    float c0r[4] = {0.f, 0.f, 0.f, 0.f};
    float c1r[4] = {0.f, 0.f, 0.f, 0.f};
    __syncthreads();

    for (int t = 0; t < WIN_SZ; ++t) {
        const int rb = t & 1, wb = rb ^ 1;

        // ---- layer 0: gates = b0 + Wx0*x_t + h0_prev @ Wh0^T
        const float4 xt = *(const float4*)&xls[t][kl * 4];
        float xa[4] = {xt.x, xt.y, xt.z, xt.w};
        f32x4 acc[4];
#pragma unroll
        for (int ns = 0; ns < 4; ++ns)
#pragma unroll
            for (int r = 0; r < 4; ++r)
                acc[ns][r] = b0r[ns] + wx0r[ns] * xa[r];
#pragma unroll
        for (int kt = 0; kt < 4; ++kt) {
            const bf16x8 a = *(const bf16x8*)&h0s[rb][cc][kt * 32 + kl * 8];
#pragma unroll
            for (int ns = 0; ns < 4; ++ns)
                acc[ns] = __builtin_amdgcn_mfma_f32_16x16x32_bf16(a, wB0[ns][kt], acc[ns], 0, 0, 0);
        }
        // in-register gate nonlinearity; C layout: row = kl*4+r (batch), col = cc (unit)
#pragma unroll
        for (int r = 0; r < 4; ++r) {
            const float ig = fsig(acc[0][r]);
            const float fg = fsig(acc[1][r]);
            const float gg = ftanh(acc[2][r]);
            const float og = fsig(acc[3][r]);
            const float c  = fg * c0r[r] + ig * gg;
            c0r[r] = c;
            h0s[wb][kl * 4 + r][w * 16 + cc] = (__bf16)(og * ftanh(c));
        }
        __syncthreads();   // h0_new visible to all waves

        // ---- layer 1: gates = b1 + h0_new @ Wx1^T + h1_prev @ Wh1^T
#pragma unroll
        for (int ns = 0; ns < 4; ++ns)
#pragma unroll
            for (int r = 0; r < 4; ++r)
                acc[ns][r] = b1r[ns];
#pragma unroll
        for (int kt = 0; kt < 8; ++kt) {
            const bf16x8 a = (kt < 4)
                ? *(const bf16x8*)&h0s[wb][cc][kt * 32 + kl * 8]
                : *(const bf16x8*)&h1s[rb][cc][(kt - 4) * 32 + kl * 8];
#pragma unroll
            for (int ns = 0; ns < 4; ++ns)
                acc[ns] = __builtin_amdgcn_mfma_f32_16x16x32_bf16(a, wB1[ns][kt], acc[ns], 0, 0, 0);
        }
#pragma unroll
        for (int r = 0; r < 4; ++r) {
            const float ig = fsig(acc[0][r]);
            const float fg = fsig(acc[1][r]);
            const float gg = ftanh(acc[2][r]);
            const float og = fsig(acc[3][r]);
            const float c  = fg * c1r[r] + ig * gg;
            c1r[r] = c;
            h1s[wb][kl * 4 + r][w * 16 + cc] = (__bf16)(og * ftanh(c));
        }
        // no trailing barrier needed: next step's barrier orders h1[wb] reads
    }
    __syncthreads();   // final h1 writes (t=167 wrote buffer 0)

    for (int i = tid; i < BB * H_SZ; i += 512) {
        const int m = i >> 7, k = i & 127;
        const int nn = base + m;
        if (nn < N_WIN) hfin[nn * H_SZ + k] = (float)h1s[0][m][k];
    }
}

// ---------------------------------------------------------------------------
// Phase D: head — feat = tanh(h @ tanh_W^T + tanh_b); out = feat @ lin_W^T + lin_b
// ---------------------------------------------------------------------------
__global__ __launch_bounds__(128) void head_kernel(
    const float* __restrict__ hfin,
    const float* __restrict__ tanhWT,
    const float* __restrict__ tanhB,
    const float* __restrict__ linW,
    const float* __restrict__ linB,
    float* __restrict__ out) {
    __shared__ float hl[H_SZ];
    __shared__ float fl[H_SZ];
    const int nn = blockIdx.x;
    const int m = threadIdx.x;
    hl[m] = hfin[nn * H_SZ + m];
    __syncthreads();
    float acc = tanhB[m];
    for (int k = 0; k < H_SZ; ++k) acc += hl[k] * tanhWT[k * H_SZ + m];
    fl[m] = tanhf(acc);
    __syncthreads();
    if (m < OUT_SZ) {
        float a = linB[m];
        for (int k = 0; k < H_SZ; ++k) a += fl[k] * linW[m * H_SZ + k];
        out[nn * OUT_SZ + m] = a;
    }
}

// ---------------------------------------------------------------------------
extern "C" void kernel_launch(void* const* d_in, const int* in_sizes, int n_in,
                              void* d_out, int out_size, void* d_ws, size_t ws_size,
                              hipStream_t stream) {
    const float* x           = (const float*)d_in[0];
    const float* lvl_raw     = (const float*)d_in[1];
    const float* seas_raw    = (const float*)d_in[2];
    const float* seas_params = (const float*)d_in[3];
    const float* noise_in    = (const float*)d_in[4];
    const float* noise_lab   = (const float*)d_in[5];
    const float* Wx0         = (const float*)d_in[6];
    const float* Wh0         = (const float*)d_in[7];
    const float* b0v         = (const float*)d_in[8];
    const float* Wx1         = (const float*)d_in[9];
    const float* Wh1         = (const float*)d_in[10];
    const float* b1v         = (const float*)d_in[11];
    const float* tanhW       = (const float*)d_in[12];
    const float* tanhB       = (const float*)d_in[13];
    const float* linW        = (const float*)d_in[14];
    const float* linB        = (const float*)d_in[15];
    float* out = (float*)d_out;

    // workspace layout (float offsets; pw0/pw1 16B-aligned by construction)
    float* wsf    = (float*)d_ws;
    float* levels = wsf;                                   // 1024
    float* wsv    = levels + T_LEN;                        // 1024
    float* sqT    = wsv + T_LEN;                           // 168*833 = 139944
    float* hfin   = sqT + WIN_SZ * N_WIN;                  // 833*128 = 106624
    float* tanhWT = hfin + N_WIN * H_SZ;                   // 128*128 = 16384
    uint4* pw0    = (uint4*)(tanhWT + H_SZ * H_SZ);        // 8192 * 16B
    uint4* pw1    = (uint4*)((float*)pw0 + 32768);         // 16384 * 16B

    hipLaunchKernelGGL(es_scan_kernel, dim3(1), dim3(256), 0, stream,
                       x, lvl_raw, seas_raw, seas_params, levels, wsv);
    hipLaunchKernelGGL(prep_weights, dim3(160), dim3(256), 0, stream,
                       Wh0, Wx1, Wh1, tanhW, pw0, pw1, tanhWT);
    hipLaunchKernelGGL(window_kernel, dim3(WIN_SZ + OUT_SZ), dim3(256), 0, stream,
                       x, levels, wsv, noise_in, noise_lab, sqT, out);
    hipLaunchKernelGGL(lstm_kernel, dim3(NBLK), dim3(512), 0, stream,
                       sqT, Wx0, b0v, b1v, pw0, pw1, hfin);
    hipLaunchKernelGGL(head_kernel, dim3(N_WIN), dim3(128), 0, stream,
                       hfin, tanhWT, tanhB, linW, linB, out);
}

// Round 3
// 787.049 us; speedup vs baseline: 5.6631x; 1.0925x over previous
//
#include <hip/hip_runtime.h>
#include <math.h>

#define T_LEN   1024
#define S_SEAS  168
#define H_SZ    128
#define G_SZ    512   // 4*H
#define WIN_SZ  168
#define OUT_SZ  24
#define N_WIN   833
#define BB      16
#define NBLK    ((N_WIN + BB - 1) / BB)   // 53
#define NPAD    (NBLK * BB)               // 848

typedef __attribute__((ext_vector_type(8))) __bf16 bf16x8;
typedef __attribute__((ext_vector_type(4))) float  f32x4;

__device__ __forceinline__ float fsig(float x) {
    return __fdividef(1.0f, 1.0f + __expf(-x));
}
__device__ __forceinline__ float ftanh(float x) {
    return 1.0f - __fdividef(2.0f, __expf(2.0f * x) + 1.0f);
}

// LDS h-tile addressing: pitch 256B (128 bf16), XOR swizzle byte^=(row&7)<<4
// (m214 recipe: row-major bf16 D=128 + ds_read_b128 per row).
__device__ __forceinline__ int hswz(int row, int colByte) {
    return row * 256 + (colByte ^ ((row & 7) << 4));
}

// ---------------------------------------------------------------------------
// Phase A: Holt-Winters ES scan. Serial, but software-pipelined: w_i = buf[j]
// was final 168 iterations earlier, so prefetch w and the divide 8 iters
// ahead; the true critical chain is one FMA (level update) per step.
// ---------------------------------------------------------------------------
__global__ void es_scan_kernel(const float* __restrict__ x,
                               const float* __restrict__ lvl_raw,
                               const float* __restrict__ seas_raw,
                               const float* __restrict__ seas_params,
                               float* __restrict__ levels,
                               float* __restrict__ wsv) {
    __shared__ float xl[T_LEN];
    __shared__ float buf[S_SEAS];
    const int t = threadIdx.x;
    for (int i = t; i < T_LEN; i += 256) xl[i] = x[i];
    for (int i = t; i < S_SEAS; i += 256) {
        const float w = expf(seas_params[i]);
        buf[i] = w;
        wsv[i] = w;
    }
    __syncthreads();
    if (t == 0) {
        const float a  = 1.0f / (1.0f + expf(-lvl_raw[0]));
        const float g  = 1.0f / (1.0f + expf(-seas_raw[0]));
        const float ca = 1.0f - a, cg = 1.0f - g;
        float level = __fdividef(xl[0], buf[0]);
        levels[0] = level;
        wsv[S_SEAS] = buf[0];   // ws_full[168] = w_init[0]

        // prefetch pipeline, depth 8: slot k holds (w, a*x/w) for iter i+k
        float wq[8], tq[8];
#pragma unroll
        for (int k = 0; k < 8; ++k) {
            const int i = 1 + k;
            const float w = buf[i % S_SEAS];
            wq[k] = w;
            tq[k] = __fdividef(a * xl[i], w);
        }
        for (int i = 1; i < T_LEN; i += 8) {
#pragma unroll
            for (int s = 0; s < 8; ++s) {
                const int ii = i + s;
                if (ii >= T_LEN) break;
                const float w  = wq[s];
                const float nl = tq[s] + ca * level;      // critical chain: 1 FMA
                const float nw = cg * w + __fdividef(g * xl[ii], nl);
                levels[ii] = nl;
                buf[ii % S_SEAS] = nw;
                if (ii + S_SEAS < T_LEN) wsv[ii + S_SEAS] = nw;
                level = nl;
                const int i8 = ii + 8;                     // refill slot
                if (i8 < T_LEN) {
                    const float w8 = buf[i8 % S_SEAS];     // final since iter i8-168
                    wq[s] = w8;
                    tq[s] = __fdividef(a * xl[i8], w8);
                }
            }
        }
    }
}

// ---------------------------------------------------------------------------
// Phase B: deseasonalized log inputs (time-major sq_inT [168][833]) + labels
// (directly into d_out) + level_var_loss scalar.
// ---------------------------------------------------------------------------
__global__ __launch_bounds__(256) void window_kernel(
    const float* __restrict__ x,
    const float* __restrict__ levels,
    const float* __restrict__ wsv,
    const float* __restrict__ noise_in,
    const float* __restrict__ noise_lab,
    float* __restrict__ sqT,
    float* __restrict__ outbuf) {
    const int p = blockIdx.x;   // 0..167: window pos; 168..191: label pos
    for (int nn = threadIdx.x; nn < N_WIN; nn += 256) {
        const float lev = levels[nn + WIN_SZ];
        if (p < WIN_SZ) {
            const int tt = nn + p;
            sqT[p * N_WIN + nn] =
                logf(x[tt] / (lev * wsv[tt])) + noise_in[nn * WIN_SZ + p];
        } else {
            const int o = p - WIN_SZ;
            const int tt = nn + WIN_SZ + o;
            outbuf[N_WIN * OUT_SZ + nn * OUT_SZ + o] =
                logf(x[tt] / (lev * wsv[tt])) + noise_lab[nn * OUT_SZ + o];
        }
    }
    if (blockIdx.x == 0 && threadIdx.x == 0)
        outbuf[2 * N_WIN * OUT_SZ] = 0.0f;   // level_var_loss
}

// ---------------------------------------------------------------------------
// Weight prep: pack Wh0 / [Wx1;Wh1] into per-lane bf16 MFMA B-fragments.
// B-frag layout (m92/m97): lane l holds col n=(l&15), 8 contiguous k at
// (l>>4)*8. Fragment f for wave w, gate ns, K-tile kt at pw[f*64+l].
// ---------------------------------------------------------------------------
__global__ __launch_bounds__(256) void prep_weights(
    const float* __restrict__ Wh0,
    const float* __restrict__ Wx1,
    const float* __restrict__ Wh1,
    const float* __restrict__ tanhW,
    uint4* __restrict__ pw0,
    uint4* __restrict__ pw1,
    float* __restrict__ tanhWT) {
    const int idx = blockIdx.x * 256 + threadIdx.x;
    auto bfr = [](float f) -> unsigned int {   // fp32 -> bf16 (RNE)
        union { float f; unsigned int u; } v; v.f = f;
        return ((v.u + 0x7FFFu + ((v.u >> 16) & 1u)) >> 16) & 0xFFFFu;
    };
    if (idx < 8192) {                       // pw0: Wh0, 128 frags (8w x 4ns x 4kt)
        const int l = idx & 63, f = idx >> 6;
        const int kt = f & 3, ns = (f >> 2) & 3, w = f >> 4;
        const int g = ns * 128 + w * 16 + (l & 15);
        const int kb = kt * 32 + (l >> 4) * 8;
        const float* s = Wh0 + g * H_SZ + kb;
        uint4 o;
        unsigned int* po = &o.x;
        for (int p = 0; p < 4; ++p) po[p] = bfr(s[2 * p]) | (bfr(s[2 * p + 1]) << 16);
        pw0[idx] = o;
    } else if (idx < 8192 + 16384) {        // pw1: [Wx1 (kt<4); Wh1 (kt>=4)], 256 frags
        const int j = idx - 8192;
        const int l = j & 63, f = j >> 6;
        const int kt = f & 7, ns = (f >> 3) & 3, w = f >> 5;
        const int g = ns * 128 + w * 16 + (l & 15);
        const float* srcm = (kt < 4) ? Wx1 : Wh1;
        const int kb = (kt & 3) * 32 + (l >> 4) * 8;
        const float* s = srcm + g * H_SZ + kb;
        uint4 o;
        unsigned int* po = &o.x;
        for (int p = 0; p < 4; ++p) po[p] = bfr(s[2 * p]) | (bfr(s[2 * p + 1]) << 16);
        pw1[j] = o;
    } else if (idx < 8192 + 16384 + 16384) {  // tanh_W transpose (fp32)
        const int j = idx - 8192 - 16384;
        const int m = j >> 7, k = j & 127;
        tanhWT[k * H_SZ + m] = tanhW[j];
    }
}

// ---------------------------------------------------------------------------
// Phase C0: layer-0 LSTM. Weights = Wh0 only -> 64 weight VGPRs/thread.
// Writes full hidden sequence hs0 [168][NPAD][128] bf16 for layer 1.
// ---------------------------------------------------------------------------
__global__
__attribute__((amdgpu_flat_work_group_size(512, 512), amdgpu_waves_per_eu(2, 2)))
void l0_kernel(const float* __restrict__ sqT,
               const float* __restrict__ Wx0,
               const float* __restrict__ b0v,
               const uint4* __restrict__ pw0,
               __bf16* __restrict__ hs0) {
    __shared__ __bf16 hls[2][16 * 128];   // swizzled, pitch 256B
    __shared__ float  xls[WIN_SZ][16];

    const int tid  = threadIdx.x;
    const int w    = tid >> 6;
    const int lane = tid & 63;
    const int cc   = lane & 15;
    const int kl   = lane >> 4;
    const int base = blockIdx.x * BB;

    for (int i = tid; i < WIN_SZ * BB; i += 512) {
        const int t = i >> 4, m = i & 15;
        const int nn = base + m;
        xls[t][m] = (nn < N_WIN) ? sqT[t * N_WIN + nn] : 0.0f;
    }
    for (int i = tid; i < 2 * 16 * 128; i += 512) (&hls[0][0])[i] = (__bf16)0.0f;

    const bf16x8* p0 = (const bf16x8*)pw0;
    bf16x8 wB0[4][4];
#pragma unroll
    for (int ns = 0; ns < 4; ++ns)
#pragma unroll
        for (int kt = 0; kt < 4; ++kt)
            wB0[ns][kt] = p0[((w * 4 + ns) * 4 + kt) * 64 + lane];

    float b0r[4], wx0r[4];
#pragma unroll
    for (int ns = 0; ns < 4; ++ns) {
        const int g = ns * 128 + w * 16 + cc;
        b0r[ns]  = b0v[g];
        wx0r[ns] = Wx0[g];
    }
    float c0r[4] = {0.f, 0.f, 0.f, 0.f};
    __syncthreads();

    char* const lbase = (char*)&hls[0][0];
    for (int t = 0; t < WIN_SZ; ++t) {
        const int rb = t & 1, wb = rb ^ 1;

        const float4 xt = *(const float4*)&xls[t][kl * 4];
        const float xa[4] = {xt.x, xt.y, xt.z, xt.w};
        f32x4 acc[4];
#pragma unroll
        for (int ns = 0; ns < 4; ++ns)
#pragma unroll
            for (int r = 0; r < 4; ++r)
                acc[ns][r] = b0r[ns] + wx0r[ns] * xa[r];
#pragma unroll
        for (int kt = 0; kt < 4; ++kt) {
            const bf16x8 a = *(const bf16x8*)(lbase + rb * 4096 + hswz(cc, kt * 64 + kl * 16));
#pragma unroll
            for (int ns = 0; ns < 4; ++ns)
                acc[ns] = __builtin_amdgcn_mfma_f32_16x16x32_bf16(a, wB0[ns][kt], acc[ns], 0, 0, 0);
        }
#pragma unroll
        for (int r = 0; r < 4; ++r) {
            const float ig = fsig(acc[0][r]);
            const float fg = fsig(acc[1][r]);
            const float gg = ftanh(acc[2][r]);
            const float og = fsig(acc[3][r]);
            const float c  = fg * c0r[r] + ig * gg;
            c0r[r] = c;
            const __bf16 hb = (__bf16)(og * ftanh(c));
            const int row = kl * 4 + r;
            *(__bf16*)(lbase + wb * 4096 + hswz(row, (w * 16 + cc) * 2)) = hb;
            hs0[t * (NPAD * H_SZ) + (base + row) * H_SZ + w * 16 + cc] = hb;
        }
        __syncthreads();
    }
}

// ---------------------------------------------------------------------------
// Phase C1: layer-1 LSTM. Weights = Wx1+Wh1 -> 128 weight VGPRs/thread.
// A-operand of the Wx1 term streams from global hs0 with 1-step prefetch.
// Final hidden written register->hfin (no LDS round-trip).
// ---------------------------------------------------------------------------
__global__
__attribute__((amdgpu_flat_work_group_size(512, 512), amdgpu_waves_per_eu(2, 2)))
void l1_kernel(const __bf16* __restrict__ hs0,
               const float* __restrict__ b1v,
               const uint4* __restrict__ pw1,
               float* __restrict__ hfin) {
    __shared__ __bf16 hls[2][16 * 128];   // swizzled h1 state

    const int tid  = threadIdx.x;
    const int w    = tid >> 6;
    const int lane = tid & 63;
    const int cc   = lane & 15;
    const int kl   = lane >> 4;
    const int base = blockIdx.x * BB;

    for (int i = tid; i < 2 * 16 * 128; i += 512) (&hls[0][0])[i] = (__bf16)0.0f;

    const bf16x8* p1 = (const bf16x8*)pw1;
    bf16x8 wX[4][4], wH[4][4];
#pragma unroll
    for (int ns = 0; ns < 4; ++ns)
#pragma unroll
        for (int kt = 0; kt < 4; ++kt) {
            wX[ns][kt] = p1[((w * 4 + ns) * 8 + kt) * 64 + lane];
            wH[ns][kt] = p1[((w * 4 + ns) * 8 + kt + 4) * 64 + lane];
        }

    float b1r[4];
#pragma unroll
    for (int ns = 0; ns < 4; ++ns) b1r[ns] = b1v[ns * 128 + w * 16 + cc];
    float c1r[4] = {0.f, 0.f, 0.f, 0.f};

    // prefetch A-frags (hs0 row = batch base+cc, k = kt*32 + kl*8) for t=0
    const int arow = (base + cc) * H_SZ + kl * 8;
    bf16x8 acur[4];
#pragma unroll
    for (int kt = 0; kt < 4; ++kt)
        acur[kt] = *(const bf16x8*)&hs0[arow + kt * 32];
    __syncthreads();

    char* const lbase = (char*)&hls[0][0];
    for (int t = 0; t < WIN_SZ; ++t) {
        const int rb = t & 1, wb = rb ^ 1;

        bf16x8 anxt[4];
        if (t < WIN_SZ - 1) {
            const int o = (t + 1) * (NPAD * H_SZ) + arow;
#pragma unroll
            for (int kt = 0; kt < 4; ++kt)
                anxt[kt] = *(const bf16x8*)&hs0[o + kt * 32];
        }

        f32x4 acc[4];
#pragma unroll
        for (int ns = 0; ns < 4; ++ns)
#pragma unroll
            for (int r = 0; r < 4; ++r)
                acc[ns][r] = b1r[ns];
#pragma unroll
        for (int kt = 0; kt < 4; ++kt) {      // Wx1 term: A from global (prefetched)
#pragma unroll
            for (int ns = 0; ns < 4; ++ns)
                acc[ns] = __builtin_amdgcn_mfma_f32_16x16x32_bf16(acur[kt], wX[ns][kt], acc[ns], 0, 0, 0);
        }
#pragma unroll
        for (int kt = 0; kt < 4; ++kt) {      // Wh1 term: A = h1_prev from LDS
            const bf16x8 a = *(const bf16x8*)(lbase + rb * 4096 + hswz(cc, kt * 64 + kl * 16));
#pragma unroll
            for (int ns = 0; ns < 4; ++ns)
                acc[ns] = __builtin_amdgcn_mfma_f32_16x16x32_bf16(a, wH[ns][kt], acc[ns], 0, 0, 0);
        }
#pragma unroll
        for (int r = 0; r < 4; ++r) {
            const float ig = fsig(acc[0][r]);
            const float fg = fsig(acc[1][r]);
            const float gg = ftanh(acc[2][r]);
            const float og = fsig(acc[3][r]);
            const float c  = fg * c1r[r] + ig * gg;
            c1r[r] = c;
            const float hv = og * ftanh(c);
            const int row = kl * 4 + r;
            if (t < WIN_SZ - 1) {
                *(__bf16*)(lbase + wb * 4096 + hswz(row, (w * 16 + cc) * 2)) = (__bf16)hv;
            } else {
                const int nn = base + row;
                if (nn < N_WIN) hfin[nn * H_SZ + w * 16 + cc] = hv;
            }
        }
        if (t < WIN_SZ - 1) __syncthreads();
#pragma unroll
        for (int kt = 0; kt < 4; ++kt) acur[kt] = anxt[kt];
    }
}

// ---------------------------------------------------------------------------
// Fallback: round-2 fused kernel (correct but scratch-spills) — used only if
// ws_size can't hold the 36.5MB hs0 intermediate.
// ---------------------------------------------------------------------------
__global__ __launch_bounds__(512, 2) void lstm_fused_kernel(
    const float* __restrict__ sqT,
    const float* __restrict__ Wx0,
    const float* __restrict__ b0v,
    const float* __restrict__ b1v,
    const uint4* __restrict__ pw0,
    const uint4* __restrict__ pw1,
    float* __restrict__ hfin) {
    __shared__ __bf16 h0s[2][16][136];
    __shared__ __bf16 h1s[2][16][136];
    __shared__ float  xls[WIN_SZ][16];

    const int tid  = threadIdx.x;
    const int w    = tid >> 6;
    const int lane = tid & 63;
    const int cc   = lane & 15;
    const int kl   = lane >> 4;
    const int base = blockIdx.x * BB;

    for (int i = tid; i < WIN_SZ * BB; i += 512) {
        const int t = i >> 4, m = i & 15;
        const int nn = base + m;
        xls[t][m] = (nn < N_WIN) ? sqT[t * N_WIN + nn] : 0.0f;
    }
    for (int i = tid; i < 2 * 16 * 136; i += 512) {
        (&h0s[0][0][0])[i] = (__bf16)0.0f;
        (&h1s[0][0][0])[i] = (__bf16)0.0f;
    }
    const bf16x8* p0 = (const bf16x8*)pw0;
    const bf16x8* p1 = (const bf16x8*)pw1;
    bf16x8 wB0[4][4];
    bf16x8 wB1[4][8];
#pragma unroll
    for (int ns = 0; ns < 4; ++ns)
#pragma unroll
        for (int kt = 0; kt < 4; ++kt)
            wB0[ns][kt] = p0[((w * 4 + ns) * 4 + kt) * 64 + lane];
#pragma unroll
    for (int ns = 0; ns < 4; ++ns)
#pragma unroll
        for (int kt = 0; kt < 8; ++kt)
            wB1[ns][kt] = p1[((w * 4 + ns) * 8 + kt) * 64 + lane];

    float b0r[4], wx0r[4], b1r[4];
#pragma unroll
    for (int ns = 0; ns < 4; ++ns) {
        const int g = ns * 128 + w * 16 + cc;
        b0r[ns]  = b0v[g];
        wx0r[ns] = Wx0[g];
        b1r[ns]  = b1v[g];
    }
    float c0r[4] = {0.f, 0.f, 0.f, 0.f};
    float c1r[4] = {0.f, 0.f, 0.f, 0.f};
    __syncthreads();

    for (int t = 0; t < WIN_SZ; ++t) {
        const int rb = t & 1, wb = rb ^ 1;
        const float4 xt = *(const float4*)&xls[t][kl * 4];
        float xa[4] = {xt.x, xt.y, xt.z, xt.w};
        f32x4 acc[4];
#pragma unroll
        for (int ns = 0; ns < 4; ++ns)
#pragma unroll
            for (int r = 0; r < 4; ++r)
                acc[ns][r] = b0r[ns] + wx0r[ns] * xa[r];
#pragma unroll
        for (int kt = 0; kt < 4; ++kt) {
            const bf16x8 a = *(const bf16x8*)&h0s[rb][cc][kt * 32 + kl * 8];
#pragma unroll
            for (int ns = 0; ns < 4; ++ns)
                acc[ns] = __builtin_amdgcn_mfma_f32_16x16x32_bf16(a, wB0[ns][kt], acc[ns], 0, 0, 0);
        }
#pragma unroll
        for (int r = 0; r < 4; ++r) {
            const float ig = fsig(acc[0][r]);
            const float fg = fsig(acc[1][r]);
            const float gg = ftanh(acc[2][r]);
            const float og = fsig(acc[3][r]);
            const float c  = fg * c0r[r] + ig * gg;
            c0r[r] = c;
            h0s[wb][kl * 4 + r][w * 16 + cc] = (__bf16)(og * ftanh(c));
        }
        __syncthreads();
#pragma unroll
        for (int ns = 0; ns < 4; ++ns)
#pragma unroll
            for (int r = 0; r < 4; ++r)
                acc[ns][r] = b1r[ns];
#pragma unroll
        for (int kt = 0; kt < 8; ++kt) {
            const bf16x8 a = (kt < 4)
                ? *(const bf16x8*)&h0s[wb][cc][kt * 32 + kl * 8]
                : *(const bf16x8*)&h1s[rb][cc][(kt - 4) * 32 + kl * 8];
#pragma unroll
            for (int ns = 0; ns < 4; ++ns)
                acc[ns] = __builtin_amdgcn_mfma_f32_16x16x32_bf16(a, wB1[ns][kt], acc[ns], 0, 0, 0);
        }
#pragma unroll
        for (int r = 0; r < 4; ++r) {
            const float ig = fsig(acc[0][r]);
            const float fg = fsig(acc[1][r]);
            const float gg = ftanh(acc[2][r]);
            const float og = fsig(acc[3][r]);
            const float c  = fg * c1r[r] + ig * gg;
            c1r[r] = c;
            h1s[wb][kl * 4 + r][w * 16 + cc] = (__bf16)(og * ftanh(c));
        }
    }
    __syncthreads();
    for (int i = tid; i < BB * H_SZ; i += 512) {
        const int m = i >> 7, k = i & 127;
        const int nn = base + m;
        if (nn < N_WIN) hfin[nn * H_SZ + k] = (float)h1s[0][m][k];
    }
}

// ---------------------------------------------------------------------------
// Phase D: head — feat = tanh(h @ tanh_W^T + tanh_b); out = feat @ lin_W^T + lin_b
// ---------------------------------------------------------------------------
__global__ __launch_bounds__(128) void head_kernel(
    const float* __restrict__ hfin,
    const float* __restrict__ tanhWT,
    const float* __restrict__ tanhB,
    const float* __restrict__ linW,
    const float* __restrict__ linB,
    float* __restrict__ out) {
    __shared__ float hl[H_SZ];
    __shared__ float fl[H_SZ];
    const int nn = blockIdx.x;
    const int m = threadIdx.x;
    hl[m] = hfin[nn * H_SZ + m];
    __syncthreads();
    float acc = tanhB[m];
    for (int k = 0; k < H_SZ; ++k) acc += hl[k] * tanhWT[k * H_SZ + m];
    fl[m] = tanhf(acc);
    __syncthreads();
    if (m < OUT_SZ) {
        float a = linB[m];
        for (int k = 0; k < H_SZ; ++k) a += fl[k] * linW[m * H_SZ + k];
        out[nn * OUT_SZ + m] = a;
    }
}

// ---------------------------------------------------------------------------
extern "C" void kernel_launch(void* const* d_in, const int* in_sizes, int n_in,
                              void* d_out, int out_size, void* d_ws, size_t ws_size,
                              hipStream_t stream) {
    const float* x           = (const float*)d_in[0];
    const float* lvl_raw     = (const float*)d_in[1];
    const float* seas_raw    = (const float*)d_in[2];
    const float* seas_params = (const float*)d_in[3];
    const float* noise_in    = (const float*)d_in[4];
    const float* noise_lab   = (const float*)d_in[5];
    const float* Wx0         = (const float*)d_in[6];
    const float* Wh0         = (const float*)d_in[7];
    const float* b0v         = (const float*)d_in[8];
    const float* Wx1         = (const float*)d_in[9];
    const float* Wh1         = (const float*)d_in[10];
    const float* b1v         = (const float*)d_in[11];
    const float* tanhW       = (const float*)d_in[12];
    const float* tanhB       = (const float*)d_in[13];
    const float* linW        = (const float*)d_in[14];
    const float* linB        = (const float*)d_in[15];
    float* out = (float*)d_out;

    // workspace layout (floats; pw0/pw1/hs0 16B-aligned by construction)
    float* wsf    = (float*)d_ws;
    float* levels = wsf;                                   // 1024
    float* wsv    = levels + T_LEN;                        // 1024
    float* sqT    = wsv + T_LEN;                           // 139944
    float* hfin   = sqT + WIN_SZ * N_WIN;                  // 106624
    float* tanhWT = hfin + N_WIN * H_SZ;                   // 16384
    uint4* pw0    = (uint4*)(tanhWT + H_SZ * H_SZ);        // 8192 uint4
    uint4* pw1    = pw0 + 8192;                            // 16384 uint4
    __bf16* hs0   = (__bf16*)(pw1 + 16384);                // 168*848*128 bf16
    const size_t need = (size_t)((char*)(hs0 + (size_t)WIN_SZ * NPAD * H_SZ) - (char*)d_ws);
    const bool split = ws_size >= need;

    hipLaunchKernelGGL(es_scan_kernel, dim3(1), dim3(256), 0, stream,
                       x, lvl_raw, seas_raw, seas_params, levels, wsv);
    hipLaunchKernelGGL(prep_weights, dim3(160), dim3(256), 0, stream,
                       Wh0, Wx1, Wh1, tanhW, pw0, pw1, tanhWT);
    hipLaunchKernelGGL(window_kernel, dim3(WIN_SZ + OUT_SZ), dim3(256), 0, stream,
                       x, levels, wsv, noise_in, noise_lab, sqT, out);
    if (split) {
        hipLaunchKernelGGL(l0_kernel, dim3(NBLK), dim3(512), 0, stream,
                           sqT, Wx0, b0v, pw0, hs0);
        hipLaunchKernelGGL(l1_kernel, dim3(NBLK), dim3(512), 0, stream,
                           hs0, b1v, pw1, hfin);
    } else {
        hipLaunchKernelGGL(lstm_fused_kernel, dim3(NBLK), dim3(512), 0, stream,
                           sqT, Wx0, b0v, b1v, pw0, pw1, hfin);
    }
    hipLaunchKernelGGL(head_kernel, dim3(N_WIN), dim3(128), 0, stream,
                       hfin, tanhWT, tanhB, linW, linB, out);
}

// Round 4
// 765.990 us; speedup vs baseline: 5.8188x; 1.0275x over previous
//
#include <hip/hip_runtime.h>
#include <math.h>

#define T_LEN   1024
#define S_SEAS  168
#define H_SZ    128
#define G_SZ    512   // 4*H
#define WIN_SZ  168
#define OUT_SZ  24
#define N_WIN   833
#define BB      16
#define NBLK    ((N_WIN + BB - 1) / BB)   // 53

typedef __attribute__((ext_vector_type(8))) __bf16 bf16x8;
typedef __attribute__((ext_vector_type(4))) float  f32x4;

__device__ __forceinline__ float fsig(float x) {
    return __fdividef(1.0f, 1.0f + __expf(-x));
}
__device__ __forceinline__ float ftanh(float x) {
    return 1.0f - __fdividef(2.0f, __expf(2.0f * x) + 1.0f);
}

// LDS h-tile addressing: pitch 256B (128 bf16), XOR swizzle byte^=(row&7)<<4
// (m214 recipe). Verified in rounds 2-3 (absmax 0.002).
__device__ __forceinline__ int hswz(int row, int colByte) {
    return row * 256 + (colByte ^ ((row & 7) << 4));
}

// ---------------------------------------------------------------------------
// Phase A: Holt-Winters ES scan. Serial, software-pipelined (w known 168
// iters ahead -> prefetch + divide off the critical chain; chain = 1 FMA).
// ---------------------------------------------------------------------------
__global__ void es_scan_kernel(const float* __restrict__ x,
                               const float* __restrict__ lvl_raw,
                               const float* __restrict__ seas_raw,
                               const float* __restrict__ seas_params,
                               float* __restrict__ levels,
                               float* __restrict__ wsv) {
    __shared__ float xl[T_LEN];
    __shared__ float buf[S_SEAS];
    const int t = threadIdx.x;
    for (int i = t; i < T_LEN; i += 256) xl[i] = x[i];
    for (int i = t; i < S_SEAS; i += 256) {
        const float w = expf(seas_params[i]);
        buf[i] = w;
        wsv[i] = w;
    }
    __syncthreads();
    if (t == 0) {
        const float a  = 1.0f / (1.0f + expf(-lvl_raw[0]));
        const float g  = 1.0f / (1.0f + expf(-seas_raw[0]));
        const float ca = 1.0f - a, cg = 1.0f - g;
        float level = __fdividef(xl[0], buf[0]);
        levels[0] = level;
        wsv[S_SEAS] = buf[0];   // ws_full[168] = w_init[0]

        float wq[8], tq[8];
#pragma unroll
        for (int k = 0; k < 8; ++k) {
            const int i = 1 + k;
            const float w = buf[i % S_SEAS];
            wq[k] = w;
            tq[k] = __fdividef(a * xl[i], w);
        }
        for (int i = 1; i < T_LEN; i += 8) {
#pragma unroll
            for (int s = 0; s < 8; ++s) {
                const int ii = i + s;
                if (ii >= T_LEN) break;
                const float w  = wq[s];
                const float nl = tq[s] + ca * level;      // critical chain: 1 FMA
                const float nw = cg * w + __fdividef(g * xl[ii], nl);
                levels[ii] = nl;
                buf[ii % S_SEAS] = nw;
                if (ii + S_SEAS < T_LEN) wsv[ii + S_SEAS] = nw;
                level = nl;
                const int i8 = ii + 8;
                if (i8 < T_LEN) {
                    const float w8 = buf[i8 % S_SEAS];
                    wq[s] = w8;
                    tq[s] = __fdividef(a * xl[i8], w8);
                }
            }
        }
    }
}

// ---------------------------------------------------------------------------
// Phase B: deseasonalized log inputs (time-major sq_inT [168][833]) + labels
// (directly into d_out) + level_var_loss scalar.
// ---------------------------------------------------------------------------
__global__ __launch_bounds__(256) void window_kernel(
    const float* __restrict__ x,
    const float* __restrict__ levels,
    const float* __restrict__ wsv,
    const float* __restrict__ noise_in,
    const float* __restrict__ noise_lab,
    float* __restrict__ sqT,
    float* __restrict__ outbuf) {
    const int p = blockIdx.x;   // 0..167: window pos; 168..191: label pos
    for (int nn = threadIdx.x; nn < N_WIN; nn += 256) {
        const float lev = levels[nn + WIN_SZ];
        if (p < WIN_SZ) {
            const int tt = nn + p;
            sqT[p * N_WIN + nn] =
                logf(x[tt] / (lev * wsv[tt])) + noise_in[nn * WIN_SZ + p];
        } else {
            const int o = p - WIN_SZ;
            const int tt = nn + WIN_SZ + o;
            outbuf[N_WIN * OUT_SZ + nn * OUT_SZ + o] =
                logf(x[tt] / (lev * wsv[tt])) + noise_lab[nn * OUT_SZ + o];
        }
    }
    if (blockIdx.x == 0 && threadIdx.x == 0)
        outbuf[2 * N_WIN * OUT_SZ] = 0.0f;   // level_var_loss
}

// ---------------------------------------------------------------------------
// Weight prep: pack Wh0 / [Wx1;Wh1] into per-lane bf16 MFMA B-fragments.
// B-frag layout (m92/m97): lane l holds col n=(l&15), 8 contiguous k at
// (l>>4)*8. Fragment f for wave w, gate ns, K-tile kt at pw[f*64+l].
// ---------------------------------------------------------------------------
__global__ __launch_bounds__(256) void prep_weights(
    const float* __restrict__ Wh0,
    const float* __restrict__ Wx1,
    const float* __restrict__ Wh1,
    const float* __restrict__ tanhW,
    uint4* __restrict__ pw0,
    uint4* __restrict__ pw1,
    float* __restrict__ tanhWT) {
    const int idx = blockIdx.x * 256 + threadIdx.x;
    auto bfr = [](float f) -> unsigned int {   // fp32 -> bf16 (RNE)
        union { float f; unsigned int u; } v; v.f = f;
        return ((v.u + 0x7FFFu + ((v.u >> 16) & 1u)) >> 16) & 0xFFFFu;
    };
    if (idx < 8192) {                       // pw0: Wh0, 128 frags (8w x 4ns x 4kt)
        const int l = idx & 63, f = idx >> 6;
        const int kt = f & 3, ns = (f >> 2) & 3, w = f >> 4;
        const int g = ns * 128 + w * 16 + (l & 15);
        const int kb = kt * 32 + (l >> 4) * 8;
        const float* s = Wh0 + g * H_SZ + kb;
        uint4 o;
        unsigned int* po = &o.x;
        for (int p = 0; p < 4; ++p) po[p] = bfr(s[2 * p]) | (bfr(s[2 * p + 1]) << 16);
        pw0[idx] = o;
    } else if (idx < 8192 + 16384) {        // pw1: [Wx1 (kt<4); Wh1 (kt>=4)], 256 frags
        const int j = idx - 8192;
        const int l = j & 63, f = j >> 6;
        const int kt = f & 7, ns = (f >> 3) & 3, w = f >> 5;
        const int g = ns * 128 + w * 16 + (l & 15);
        const float* srcm = (kt < 4) ? Wx1 : Wh1;
        const int kb = (kt & 3) * 32 + (l >> 4) * 8;
        const float* s = srcm + g * H_SZ + kb;
        uint4 o;
        unsigned int* po = &o.x;
        for (int p = 0; p < 4; ++p) po[p] = bfr(s[2 * p]) | (bfr(s[2 * p + 1]) << 16);
        pw1[j] = o;
    } else if (idx < 8192 + 16384 + 16384) {  // tanh_W transpose (fp32)
        const int j = idx - 8192 - 16384;
        const int m = j >> 7, k = j & 127;
        tanhWT[k * H_SZ + m] = tanhW[j];
    }
}

// ---------------------------------------------------------------------------
// Phase C: wave-specialized fused 2-layer LSTM.
// 1024 threads = 16 waves. Waves 0-7: layer 0 at step it; waves 8-15:
// layer 1 at step it-1 (one-step software pipeline, 1 barrier/iteration).
// Per-wave resident weights: 64 VGPRs (Wh0 or Wh1). Wx1 (128KB) lives in
// LDS as packed B-frags (stride-1 ds_read_b128, conflict-free). h0/h1
// double-buffered bf16 in LDS (swizzled). No global intermediate.
// ---------------------------------------------------------------------------
__global__
__attribute__((amdgpu_flat_work_group_size(1024, 1024), amdgpu_waves_per_eu(4, 4)))
void fused_lstm_kernel(const float* __restrict__ sqT,
                       const float* __restrict__ Wx0,
                       const float* __restrict__ b0v,
                       const float* __restrict__ b1v,
                       const uint4* __restrict__ pw0,
                       const uint4* __restrict__ pw1,
                       float* __restrict__ hfin) {
    __shared__ uint4  wx1s[8192];          // 128KB packed Wx1 B-frags
    __shared__ __bf16 h0s[2][16 * 128];    // 8KB, swizzled, pitch 256B
    __shared__ __bf16 h1s[2][16 * 128];    // 8KB
    __shared__ float  xls[WIN_SZ][16];     // 10.5KB

    const int tid  = threadIdx.x;
    const int wv   = tid >> 6;            // 0..15
    const int lane = tid & 63;
    const int cc   = lane & 15;           // unit-within-wave / A-row sel
    const int kl   = lane >> 4;           // k-group; C rows = kl*4 + r
    const int base = blockIdx.x * BB;
    const bool isL0 = (wv < 8);
    const int w    = isL0 ? wv : (wv - 8);

    // stage x (time-major) for this block's 16 windows
    for (int i = tid; i < WIN_SZ * BB; i += 1024) {
        const int t = i >> 4, m = i & 15;
        const int nn = base + m;
        xls[t][m] = (nn < N_WIN) ? sqT[t * N_WIN + nn] : 0.0f;
    }
    // zero both h double-buffers
    for (int i = tid; i < 2 * 16 * 128; i += 1024) {
        (&h0s[0][0])[i] = (__bf16)0.0f;
        (&h1s[0][0])[i] = (__bf16)0.0f;
    }
    // stage Wx1 frags into LDS: frag fL=((w1*4+ns)*4+kt), 64 uint4 each
    for (int i = tid; i < 8192; i += 1024) {
        const int l = i & 63, f = i >> 6;
        const int kt = f & 3, ns = (f >> 2) & 3, w1 = f >> 4;
        wx1s[i] = pw1[((w1 * 4 + ns) * 8 + kt) * 64 + l];
    }

    // per-path resident weights (64 VGPRs) + biases
    bf16x8 wR[4][4];
    float bias[4], wx0r[4];
    if (isL0) {
        const bf16x8* p0 = (const bf16x8*)pw0;
#pragma unroll
        for (int ns = 0; ns < 4; ++ns) {
#pragma unroll
            for (int kt = 0; kt < 4; ++kt)
                wR[ns][kt] = p0[((w * 4 + ns) * 4 + kt) * 64 + lane];
            const int g = ns * 128 + w * 16 + cc;
            bias[ns] = b0v[g];
            wx0r[ns] = Wx0[g];
        }
    } else {
        const bf16x8* p1 = (const bf16x8*)pw1;
#pragma unroll
        for (int ns = 0; ns < 4; ++ns) {
#pragma unroll
            for (int kt = 0; kt < 4; ++kt)
                wR[ns][kt] = p1[((w * 4 + ns) * 8 + kt + 4) * 64 + lane];
            bias[ns] = b1v[ns * 128 + w * 16 + cc];
            wx0r[ns] = 0.0f;
        }
    }
    float cr[4] = {0.f, 0.f, 0.f, 0.f};
    __syncthreads();

    char* const hb0 = (char*)&h0s[0][0];
    char* const hb1 = (char*)&h1s[0][0];

    for (int it = 0; it <= WIN_SZ; ++it) {
        if (isL0) {
            if (it < WIN_SZ) {
                const int rs = (it - 1) & 1;   // h0[it-1] slot (zeros for it=0)
                const int wsl = it & 1;        // h0[it] slot
                const float4 xt = *(const float4*)&xls[it][kl * 4];
                const float xa[4] = {xt.x, xt.y, xt.z, xt.w};
                f32x4 acc[4];
#pragma unroll
                for (int ns = 0; ns < 4; ++ns)
#pragma unroll
                    for (int r = 0; r < 4; ++r)
                        acc[ns][r] = bias[ns] + wx0r[ns] * xa[r];
#pragma unroll
                for (int kt = 0; kt < 4; ++kt) {
                    const bf16x8 a = *(const bf16x8*)(hb0 + rs * 4096 + hswz(cc, kt * 64 + kl * 16));
#pragma unroll
                    for (int ns = 0; ns < 4; ++ns)
                        acc[ns] = __builtin_amdgcn_mfma_f32_16x16x32_bf16(a, wR[ns][kt], acc[ns], 0, 0, 0);
                }
#pragma unroll
                for (int r = 0; r < 4; ++r) {
                    const float ig = fsig(acc[0][r]);
                    const float fg = fsig(acc[1][r]);
                    const float gg = ftanh(acc[2][r]);
                    const float og = fsig(acc[3][r]);
                    const float c  = fg * cr[r] + ig * gg;
                    cr[r] = c;
                    const int row = kl * 4 + r;
                    *(__bf16*)(hb0 + wsl * 4096 + hswz(row, (w * 16 + cc) * 2)) =
                        (__bf16)(og * ftanh(c));
                }
            }
        } else {
            if (it >= 1) {
                const int tt  = it - 1;
                const int rs0 = tt & 1;         // h0[tt] slot (written last iter)
                const int rs1 = (tt - 1) & 1;   // h1[tt-1] slot (zeros for tt=0)
                const int wsl = tt & 1;         // h1[tt] slot
                f32x4 acc[4];
#pragma unroll
                for (int ns = 0; ns < 4; ++ns)
#pragma unroll
                    for (int r = 0; r < 4; ++r)
                        acc[ns][r] = bias[ns];
#pragma unroll
                for (int kt = 0; kt < 4; ++kt) {   // Wx1 term: B from LDS
                    const bf16x8 a = *(const bf16x8*)(hb0 + rs0 * 4096 + hswz(cc, kt * 64 + kl * 16));
#pragma unroll
                    for (int ns = 0; ns < 4; ++ns) {
                        const bf16x8 wb = *(const bf16x8*)&wx1s[((w * 4 + ns) * 4 + kt) * 64 + lane];
                        acc[ns] = __builtin_amdgcn_mfma_f32_16x16x32_bf16(a, wb, acc[ns], 0, 0, 0);
                    }
                }
#pragma unroll
                for (int kt = 0; kt < 4; ++kt) {   // Wh1 term: B resident
                    const bf16x8 a = *(const bf16x8*)(hb1 + rs1 * 4096 + hswz(cc, kt * 64 + kl * 16));
#pragma unroll
                    for (int ns = 0; ns < 4; ++ns)
                        acc[ns] = __builtin_amdgcn_mfma_f32_16x16x32_bf16(a, wR[ns][kt], acc[ns], 0, 0, 0);
                }
#pragma unroll
                for (int r = 0; r < 4; ++r) {
                    const float ig = fsig(acc[0][r]);
                    const float fg = fsig(acc[1][r]);
                    const float gg = ftanh(acc[2][r]);
                    const float og = fsig(acc[3][r]);
                    const float c  = fg * cr[r] + ig * gg;
                    cr[r] = c;
                    const float hv = og * ftanh(c);
                    const int row = kl * 4 + r;
                    if (tt < WIN_SZ - 1) {
                        *(__bf16*)(hb1 + wsl * 4096 + hswz(row, (w * 16 + cc) * 2)) = (__bf16)hv;
                    } else {
                        const int nn = base + row;
                        if (nn < N_WIN) hfin[nn * H_SZ + w * 16 + cc] = hv;
                    }
                }
            }
        }
        __syncthreads();
    }
}

// ---------------------------------------------------------------------------
// Phase D: head — feat = tanh(h @ tanh_W^T + tanh_b); out = feat @ lin_W^T + lin_b
// ---------------------------------------------------------------------------
__global__ __launch_bounds__(128) void head_kernel(
    const float* __restrict__ hfin,
    const float* __restrict__ tanhWT,
    const float* __restrict__ tanhB,
    const float* __restrict__ linW,
    const float* __restrict__ linB,
    float* __restrict__ out) {
    __shared__ float hl[H_SZ];
    __shared__ float fl[H_SZ];
    const int nn = blockIdx.x;
    const int m = threadIdx.x;
    hl[m] = hfin[nn * H_SZ + m];
    __syncthreads();
    float acc = tanhB[m];
    for (int k = 0; k < H_SZ; ++k) acc += hl[k] * tanhWT[k * H_SZ + m];
    fl[m] = tanhf(acc);
    __syncthreads();
    if (m < OUT_SZ) {
        float a = linB[m];
        for (int k = 0; k < H_SZ; ++k) a += fl[k] * linW[m * H_SZ + k];
        out[nn * OUT_SZ + m] = a;
    }
}

// ---------------------------------------------------------------------------
extern "C" void kernel_launch(void* const* d_in, const int* in_sizes, int n_in,
                              void* d_out, int out_size, void* d_ws, size_t ws_size,
                              hipStream_t stream) {
    const float* x           = (const float*)d_in[0];
    const float* lvl_raw     = (const float*)d_in[1];
    const float* seas_raw    = (const float*)d_in[2];
    const float* seas_params = (const float*)d_in[3];
    const float* noise_in    = (const float*)d_in[4];
    const float* noise_lab   = (const float*)d_in[5];
    const float* Wx0         = (const float*)d_in[6];
    const float* Wh0         = (const float*)d_in[7];
    const float* b0v         = (const float*)d_in[8];
    const float* Wx1         = (const float*)d_in[9];
    const float* Wh1         = (const float*)d_in[10];
    const float* b1v         = (const float*)d_in[11];
    const float* tanhW       = (const float*)d_in[12];
    const float* tanhB       = (const float*)d_in[13];
    const float* linW        = (const float*)d_in[14];
    const float* linB        = (const float*)d_in[15];
    float* out = (float*)d_out;

    // workspace layout (floats; pw0/pw1 16B-aligned by construction)
    float* wsf    = (float*)d_ws;
    float* levels = wsf;                                   // 1024
    float* wsv    = levels + T_LEN;                        // 1024
    float* sqT    = wsv + T_LEN;                           // 139944
    float* hfin   = sqT + WIN_SZ * N_WIN;                  // 106624
    float* tanhWT = hfin + N_WIN * H_SZ;                   // 16384
    uint4* pw0    = (uint4*)(tanhWT + H_SZ * H_SZ);        // 8192 uint4
    uint4* pw1    = pw0 + 8192;                            // 16384 uint4

    hipLaunchKernelGGL(es_scan_kernel, dim3(1), dim3(256), 0, stream,
                       x, lvl_raw, seas_raw, seas_params, levels, wsv);
    hipLaunchKernelGGL(prep_weights, dim3(160), dim3(256), 0, stream,
                       Wh0, Wx1, Wh1, tanhW, pw0, pw1, tanhWT);
    hipLaunchKernelGGL(window_kernel, dim3(WIN_SZ + OUT_SZ), dim3(256), 0, stream,
                       x, levels, wsv, noise_in, noise_lab, sqT, out);
    hipLaunchKernelGGL(fused_lstm_kernel, dim3(NBLK), dim3(1024), 0, stream,
                       sqT, Wx0, b0v, b1v, pw0, pw1, hfin);
    hipLaunchKernelGGL(head_kernel, dim3(N_WIN), dim3(128), 0, stream,
                       hfin, tanhWT, tanhB, linW, linB, out);
}